// Round 9
// baseline (792.191 us; speedup 1.0000x reference)
//
#include <hip/hip_runtime.h>
#include <hip/hip_bf16.h>
#include <math.h>

typedef short bf16x8 __attribute__((ext_vector_type(8)));
typedef float f32x4 __attribute__((ext_vector_type(4)));
typedef unsigned int u32;
typedef unsigned short u16;

#define DIM 128
#define ATTN_EPS 3.1622776601683794e-4f   // float(sqrt(1e-7))
#define DIV_EPS 1e-7f
#define SCAN_BLKS 256

__device__ __forceinline__ u16 f2b(float f) {            // f32 -> bf16 bits (RNE)
  u32 u = __float_as_uint(f);
  return (u16)((u + 0x7FFFu + ((u >> 16) & 1u)) >> 16);
}
__device__ __forceinline__ float b2f(u16 s) { return __uint_as_float(((u32)s) << 16); }
// mish(v) = v*tanh(softplus(v)) = v*(w^2-1)/(w^2+1), w = 1+e^v  (clamped: v>15 -> tanh==1)
__device__ __forceinline__ float mish_f(float v) {
  float e = __expf(fminf(v, 15.f));
  float w = 1.f + e;
  return v * (1.f - 2.f * __builtin_amdgcn_rcpf(w * w + 1.f));
}

// ---- staging helpers: tiles are [rows][136] u16 (pad +8 breaks 256B bank stride) ----
template <int NT, int NR>
__device__ __forceinline__ void stage_f32(u16 (*dst)[136], const float* __restrict__ src,
                                          long rowbase, long nrows, int tid) {
  #pragma unroll
  for (int it = 0; it < NR * 16 / NT; ++it) {
    int i = it * NT + tid;
    int r = i >> 4, c = (i & 15) * 8;
    long gr = rowbase + r;
    bf16x8 v;
    if (gr < nrows) {
      const f32x4* p = (const f32x4*)(src + gr * (long)DIM + c);
      f32x4 a = p[0], b = p[1];
      #pragma unroll
      for (int j = 0; j < 4; ++j) { v[j] = (short)f2b(a[j]); v[j + 4] = (short)f2b(b[j]); }
    } else {
      #pragma unroll
      for (int j = 0; j < 8; ++j) v[j] = 0;
    }
    *(bf16x8*)&dst[r][c] = v;
  }
}

template <int NT, int NR>
__device__ __forceinline__ void stage_b16(u16 (*dst)[136], const u16* __restrict__ src, int tid) {
  #pragma unroll
  for (int it = 0; it < NR * 16 / NT; ++it) {
    int i = it * NT + tid;
    int r = i >> 4, c = (i & 15) * 8;
    *(bf16x8*)&dst[r][c] = *(const bf16x8*)&src[(long)r * DIM + c];
  }
}

// gather nm[idx[row]][segoff..segoff+128) into LDS tile, vectorized 16B/lane
template <int NT, int NR>
__device__ __forceinline__ void gather_nm(u16 (*dst)[136], const u16* __restrict__ nm,
    const int* __restrict__ idx, int segoff, long rowbase, long nrows, int tid) {
  #pragma unroll
  for (int it = 0; it < NR * 16 / NT; ++it) {
    int i = it * NT + tid;
    int r = i >> 4, c = (i & 15) * 8;
    long gr = rowbase + r;
    bf16x8 v;
    if (gr < nrows) {
      v = *(const bf16x8*)&nm[(long)idx[gr] * 512 + segoff + c];
    } else {
      #pragma unroll
      for (int j = 0; j < 8; ++j) v[j] = 0;
    }
    *(bf16x8*)&dst[r][c] = v;
  }
}

// ---- MFMA core, A and B from LDS. C/D: col=lane&15, row=(lane>>4)*4+j (verified) ----
__device__ __forceinline__ void mm_32x64(const u16 (*As)[136], const u16 (*Bs)[136],
                                         int wr, int wc, int lane, f32x4 acc[2][4]) {
  int r0 = wr * 32 + (lane & 15);
  int cb = wc * 64 + (lane & 15);
  int koff = (lane >> 4) * 8;
  #pragma unroll
  for (int ks = 0; ks < 4; ++ks) {
    int k = ks * 32 + koff;
    bf16x8 a0 = *(const bf16x8*)&As[r0][k];
    bf16x8 a1 = *(const bf16x8*)&As[r0 + 16][k];
    #pragma unroll
    for (int ct = 0; ct < 4; ++ct) {
      bf16x8 b = *(const bf16x8*)&Bs[cb + ct * 16][k];
      acc[0][ct] = __builtin_amdgcn_mfma_f32_16x16x32_bf16(a0, b, acc[0][ct], 0, 0, 0);
      acc[1][ct] = __builtin_amdgcn_mfma_f32_16x16x32_bf16(a1, b, acc[1][ct], 0, 0, 0);
    }
  }
}

// ---- prep: transpose weights to [Cout][K] bf16 + zero deg ----
__global__ void k_prep(const float* __restrict__ Wni, const float* __restrict__ Wei,
                       const float* __restrict__ Wno, const float* __restrict__ Weo,
                       u16* __restrict__ Tni, u16* __restrict__ Tei,
                       u16* __restrict__ Tno, u16* __restrict__ Teo,
                       u32* __restrict__ deg, int N) {
  int stride = gridDim.x * blockDim.x;
  int t0 = blockIdx.x * blockDim.x + threadIdx.x;
  for (int i = t0; i < 128 * 512; i += stride) { int k = i >> 9, c = i & 511; Tni[c * 128 + k] = f2b(Wni[i]); }
  for (int i = t0; i < 128 * 384; i += stride) { int k = i / 384, c = i % 384; Tei[c * 128 + k] = f2b(Wei[i]); }
  for (int i = t0; i < 128 * 128; i += stride) { int k = i >> 7, c = i & 127; Tno[c * 128 + k] = f2b(Wno[i]); }
  for (int i = t0; i < 128 * 128; i += stride) { int k = i >> 7, c = i & 127; Teo[c * 128 + k] = f2b(Weo[i]); }
  for (int i = t0; i < N; i += stride) deg[i] = 0;
}

// ---- node input GEMM: nm[N][512] = bf16(x) @ W_node_in; x staged ONCE, 4 chunk loop ----
__global__ __launch_bounds__(512, 4) void k_node_in(const float* __restrict__ x,
    const u16* __restrict__ Tni, u16* __restrict__ nm, int N) {
  __shared__ u16 As[128][136];
  __shared__ u16 Bs[128][136];
  int tid = threadIdx.x, lane = tid & 63;
  int wid = tid >> 6, wr = wid >> 1, wc = wid & 1;
  long rowbase = (long)blockIdx.x * 128;
  stage_f32<512, 128>(As, x, rowbase, N, tid);
  stage_b16<512, 128>(Bs, Tni, tid);
  __syncthreads();
  #pragma unroll 1
  for (int chunk = 0; chunk < 4; ++chunk) {
    f32x4 acc[2][4] = {};
    mm_32x64(As, Bs, wr, wc, lane, acc);
    __syncthreads();                                       // Bs reads done
    if (chunk < 3) stage_b16<512, 128>(Bs, Tni + (chunk + 1) * 128 * DIM, tid);
    #pragma unroll
    for (int rt = 0; rt < 2; ++rt)
    #pragma unroll
    for (int j = 0; j < 4; ++j) {
      int lr = wr * 32 + rt * 16 + ((lane >> 4) << 2) + j;
      long r = rowbase + lr;
      if (r >= N) continue;
      #pragma unroll
      for (int ct = 0; ct < 4; ++ct) {
        int col = wc * 64 + ct * 16 + (lane & 15);
        nm[r * 512 + chunk * 128 + col] = f2b(acc[rt][ct][j]);
      }
    }
    if (chunk < 3) __syncthreads();                        // new Bs staged
  }
}

// ---- edge pass (R7 structure, 128-edge tile, 2 blocks/CU) + hoisted residual ea ----
__global__ __launch_bounds__(512, 4) void k_edge_in(const float* __restrict__ ea,
    const u16* __restrict__ Tei, const u16* __restrict__ Teo,
    const u16* __restrict__ nm, const int* __restrict__ head, const int* __restrict__ tail,
    const float* __restrict__ ebias, const float* __restrict__ beo,
    u32* __restrict__ em, float* __restrict__ eout, int E) {
  __shared__ u16 As[128][136];   // ea tile -> t2e -> H (mish) tile
  __shared__ u16 Bs[128][136];   // W_e2t -> W_msg -> n2n -> W_e2s -> h2e -> W_eo
  int tid = threadIdx.x, lane = tid & 63;
  int wid = tid >> 6, wr = wid >> 1, wc = wid & 1;   // 8 waves: 4 row x 2 col
  long rowbase = (long)blockIdx.x * 128;
  int col0 = wc * 64 + (lane & 15);

  stage_f32<512, 128>(As, ea, rowbase, E, tid);
  stage_b16<512, 128>(Bs, Tei + 128 * DIM, tid);       // edge_to_tail cols
  // hoist the residual ea reads: same lines as the staging loads -> L1/L2 hits now,
  // instead of L3-latency re-reads 40us later in the final epilogue
  float ea_own[2][4][4];
  #pragma unroll
  for (int rt = 0; rt < 2; ++rt)
  #pragma unroll
  for (int j = 0; j < 4; ++j) {
    int lr = wr * 32 + rt * 16 + ((lane >> 4) << 2) + j;
    long r = rowbase + lr;
    #pragma unroll
    for (int ct = 0; ct < 4; ++ct) {
      int col = col0 + ct * 16;
      ea_own[rt][j][ct] = (r < E) ? ea[r * (long)DIM + col] : 0.f;
    }
  }
  __syncthreads();
  f32x4 acc_t[2][4] = {};
  mm_32x64(As, Bs, wr, wc, lane, acc_t);
  __syncthreads();
  stage_b16<512, 128>(Bs, Tei + 256 * DIM, tid);       // attn-message cols
  __syncthreads();
  f32x4 acc_m[2][4] = {};
  mm_32x64(As, Bs, wr, wc, lane, acc_m);
  __syncthreads();
  gather_nm<512, 128>(Bs, nm, head, 128, rowbase, E, tid);   // n2n[head]
  __syncthreads();
  // epilogue 1: em[r][col] = pack(bf16(n2n + e2t), bf16(msg))
  #pragma unroll
  for (int rt = 0; rt < 2; ++rt)
  #pragma unroll
  for (int j = 0; j < 4; ++j) {
    int lr = wr * 32 + rt * 16 + ((lane >> 4) << 2) + j;
    long r = rowbase + lr;
    if (r < E) {
      #pragma unroll
      for (int ct = 0; ct < 4; ++ct) {
        int col = col0 + ct * 16;
        float n2n = b2f(Bs[lr][col]);
        em[r * 128 + col] = (u32)f2b(n2n + acc_t[rt][ct][j])
                          | ((u32)f2b(acc_m[rt][ct][j]) << 16);
      }
    }
  }
  __syncthreads();
  stage_b16<512, 128>(Bs, Tei, tid);                   // edge_to_self cols
  __syncthreads();
  f32x4 acc_s[2][4] = {};
  mm_32x64(As, Bs, wr, wc, lane, acc_s);               // last use of ea tile
  __syncthreads();
  gather_nm<512, 128>(Bs, nm, head, 256, rowbase, E, tid);   // h2e
  gather_nm<512, 128>(As, nm, tail, 384, rowbase, E, tid);   // t2e (As dead)
  __syncthreads();
  // epilogue 2: H = bf16(mish(e2s + h2e + t2e + eb)), in place over t2e (owner slots)
  #pragma unroll
  for (int rt = 0; rt < 2; ++rt)
  #pragma unroll
  for (int j = 0; j < 4; ++j) {
    int lr = wr * 32 + rt * 16 + ((lane >> 4) << 2) + j;
    long r = rowbase + lr;
    #pragma unroll
    for (int ct = 0; ct < 4; ++ct) {
      int col = col0 + ct * 16;
      if (r < E) {
        float epre = acc_s[rt][ct][j] + b2f(Bs[lr][col]) + b2f(As[lr][col]) + ebias[col];
        As[lr][col] = f2b(mish_f(epre));
      } else {
        As[lr][col] = 0;
      }
    }
  }
  __syncthreads();
  stage_b16<512, 128>(Bs, Teo, tid);                   // W_edge_out^T
  __syncthreads();
  f32x4 acc_o[2][4] = {};
  mm_32x64(As, Bs, wr, wc, lane, acc_o);
  #pragma unroll
  for (int rt = 0; rt < 2; ++rt)
  #pragma unroll
  for (int j = 0; j < 4; ++j) {
    int lr = wr * 32 + rt * 16 + ((lane >> 4) << 2) + j;
    long r = rowbase + lr;
    if (r >= E) continue;
    #pragma unroll
    for (int ct = 0; ct < 4; ++ct) {
      int col = col0 + ct * 16;
      eout[r * DIM + col] = ea_own[rt][j][ct] + acc_o[rt][ct][j] + beo[col];
    }
  }
}

// ---- CSR build ----
__global__ void k_count(const int* __restrict__ tail, u32* __restrict__ deg, int E) {
  int i = blockIdx.x * blockDim.x + threadIdx.x;
  int stride = gridDim.x * blockDim.x;
  for (; i < E; i += stride) atomicAdd(&deg[tail[i]], 1u);
}
__global__ __launch_bounds__(256) void k_scan_part(const u32* __restrict__ deg,
                                                   u32* __restrict__ part, int N) {
  __shared__ u32 red[256];
  int tid = threadIdx.x, b = blockIdx.x;
  int chunk = (N + SCAN_BLKS - 1) / SCAN_BLKS;
  int lo = b * chunk, hi = min(lo + chunk, N);
  u32 s = 0;
  for (int i = lo + tid; i < hi; i += 256) s += deg[i];
  red[tid] = s; __syncthreads();
  for (int st = 128; st > 0; st >>= 1) { if (tid < st) red[tid] += red[tid + st]; __syncthreads(); }
  if (tid == 0) part[b] = red[0];
}
__global__ __launch_bounds__(256) void k_scan_mid(u32* __restrict__ part) {
  __shared__ u32 lds[256];
  int tid = threadIdx.x;
  u32 v = part[tid];
  lds[tid] = v; __syncthreads();
  for (int s = 1; s < 256; s <<= 1) {
    u32 a = (tid >= s) ? lds[tid - s] : 0; __syncthreads();
    lds[tid] += a; __syncthreads();
  }
  part[tid] = lds[tid] - v;   // exclusive
}
__global__ __launch_bounds__(256) void k_scan_fin(const u32* __restrict__ deg,
    const u32* __restrict__ part, u32* __restrict__ off, u32* __restrict__ cur, int N) {
  __shared__ u32 lds[256];
  int tid = threadIdx.x, b = blockIdx.x;
  int chunk = (N + SCAN_BLKS - 1) / SCAN_BLKS;
  int lo = b * chunk, hi = min(lo + chunk, N);
  u32 carry = part[b];
  for (int base = lo; base < hi; base += 256) {
    int i = base + tid;
    u32 v = (i < hi) ? deg[i] : 0;
    lds[tid] = v; __syncthreads();
    for (int s = 1; s < 256; s <<= 1) {
      u32 a = (tid >= s) ? lds[tid - s] : 0; __syncthreads();
      lds[tid] += a; __syncthreads();
    }
    u32 incl = lds[tid], total = lds[255];
    __syncthreads();
    if (i < hi) { u32 o = carry + incl - v; off[i] = o; cur[i] = o; }
    carry += total;
  }
}
__global__ void k_fill(const int* __restrict__ tail, u32* __restrict__ cur,
                       u32* __restrict__ csr, int E) {
  int i = blockIdx.x * blockDim.x + threadIdx.x;
  int stride = gridDim.x * blockDim.x;
  for (; i < E; i += stride) { u32 p = atomicAdd(&cur[tail[i]], 1u); csr[p] = (u32)i; }
}

// ---- per-node gather + online softmax + divide + mish -> hbuf; 1 node/wave,
//      8-deep batched loads (pads are val=0,msg=-inf: algebraically neutral) ----
__global__ __launch_bounds__(256, 6) void k_node_agg(const u32* __restrict__ em,
    const u16* __restrict__ nm, const u32* __restrict__ off, const u32* __restrict__ deg,
    const u32* __restrict__ csr, const float* __restrict__ nbias,
    u16* __restrict__ hbuf, int N) {
  int tid = threadIdx.x, lane = tid & 63;
  int node = blockIdx.x * 4 + (tid >> 6);
  if (node >= N) return;
  int ch = lane * 2;
  u32 o = __builtin_amdgcn_readfirstlane(off[node]);
  u32 d = __builtin_amdgcn_readfirstlane(deg[node]);
  float m0 = -INFINITY, m1 = -INFINITY;
  float s0 = 0.f, s1 = 0.f, v0 = 0.f, v1 = 0.f, sv0 = 0.f, sv1 = 0.f;
  for (u32 i = 0; i < d; i += 8) {
    uint2 b[8];
    #pragma unroll
    for (int j = 0; j < 8; ++j) {
      if (i + j < d) {
        u32 e = csr[o + i + j];
        b[j] = *(const uint2*)(em + (long)e * 128 + ch);
      } else {
        b[j].x = 0xFF800000u; b[j].y = 0xFF800000u;   // val=0, msg=-inf
      }
    }
    #pragma unroll
    for (int j = 0; j < 8; ++j) {
      float val0 = b2f((u16)(b[j].x & 0xffff)), g0 = b2f((u16)(b[j].x >> 16));
      float val1 = b2f((u16)(b[j].y & 0xffff)), g1 = b2f((u16)(b[j].y >> 16));
      float nmx0 = fmaxf(m0, g0);
      float sc0 = __expf(m0 - nmx0), pe0 = __expf(g0 - nmx0);
      s0 = s0 * sc0 + pe0; v0 = v0 * sc0 + pe0 * val0; sv0 += val0; m0 = nmx0;
      float nmx1 = fmaxf(m1, g1);
      float sc1 = __expf(m1 - nmx1), pe1 = __expf(g1 - nmx1);
      s1 = s1 * sc1 + pe1; v1 = v1 * sc1 + pe1 * val1; sv1 += val1; m1 = nmx1;
    }
  }
  // weight_e = exp(msg-M)+eps  =>  Σw = s + d*eps ; Σ(w*val) = v + eps*Σval
  float de = (float)d * ATTN_EPS;
  float r0 = (v0 + ATTN_EPS * sv0) * __builtin_amdgcn_rcpf(s0 + de + DIV_EPS);
  float r1 = (v1 + ATTN_EPS * sv1) * __builtin_amdgcn_rcpf(s1 + de + DIV_EPS);
  u32 np = *(const u32*)&nm[(long)node * 512 + ch];
  float h0 = mish_f(r0 + b2f((u16)(np & 0xffff)) + nbias[ch]);
  float h1 = mish_f(r1 + b2f((u16)(np >> 16)) + nbias[ch + 1]);
  *(u32*)&hbuf[(long)node * 128 + ch] = (u32)f2b(h0) | ((u32)f2b(h1) << 16);
}

// ---- node output: x_out = x + h @ W_node_out + b ----
__global__ __launch_bounds__(256) void k_node_out(const float* __restrict__ x,
    const u16* __restrict__ hbuf, const u16* __restrict__ Tno, const float* __restrict__ bno,
    float* __restrict__ xout, int N) {
  __shared__ u16 As[64][136];
  __shared__ u16 Bs[128][136];
  int tid = threadIdx.x, lane = tid & 63;
  int wid = tid >> 6, wr = wid >> 1, wc = wid & 1;
  long rowbase = (long)blockIdx.x * 64;
  stage_b16<256, 64>(As, hbuf + rowbase * DIM, tid);   // hbuf padded to tile multiple
  stage_b16<256, 128>(Bs, Tno, tid);
  __syncthreads();
  f32x4 acc[2][4] = {};
  mm_32x64(As, Bs, wr, wc, lane, acc);
  #pragma unroll
  for (int rt = 0; rt < 2; ++rt)
  #pragma unroll
  for (int j = 0; j < 4; ++j) {
    int lr = wr * 32 + rt * 16 + ((lane >> 4) << 2) + j;
    long r = rowbase + lr;
    if (r >= N) continue;
    #pragma unroll
    for (int ct = 0; ct < 4; ++ct) {
      int col = wc * 64 + ct * 16 + (lane & 15);
      xout[r * DIM + col] = x[r * DIM + col] + acc[rt][ct][j] + bno[col];
    }
  }
}

extern "C" void kernel_launch(void* const* d_in, const int* in_sizes, int n_in,
                              void* d_out, int out_size, void* d_ws, size_t ws_size,
                              hipStream_t stream) {
  const float* x     = (const float*)d_in[0];
  const float* ea    = (const float*)d_in[1];
  const int*   head  = (const int*)d_in[2];
  const int*   tail  = (const int*)d_in[3];
  const float* Wni   = (const float*)d_in[8];
  const float* Wei   = (const float*)d_in[9];
  const float* nbias = (const float*)d_in[10];
  const float* ebias = (const float*)d_in[11];
  const float* Wno   = (const float*)d_in[12];
  const float* bno   = (const float*)d_in[13];
  const float* Weo   = (const float*)d_in[14];
  const float* beo   = (const float*)d_in[15];
  const int N = in_sizes[0] / DIM;
  const int E = in_sizes[1] / DIM;
  const int NB64 = (N + 63) / 64;
  const int NB128 = (N + 127) / 128;
  const int EB = (E + 127) / 128;
  const int NPAD = NB64 * 64;

  char* ws = (char*)d_ws;
  u16*   nm   = (u16*)ws; ws += (size_t)N * 512 * 2;      // node messages bf16 [N][512]
  u32*   em   = (u32*)ws; ws += (size_t)E * 128 * 4;      // packed val|msg, edge order [E][128]
  u16*   hbuf = (u16*)ws; ws += (size_t)NPAD * 128 * 2;   // mish(node path) bf16
  u32*   deg  = (u32*)ws; ws += (size_t)N * 4;
  u32*   off  = (u32*)ws; ws += (size_t)N * 4;
  u32*   cur  = (u32*)ws; ws += (size_t)N * 4;
  u32*   part = (u32*)ws; ws += (size_t)SCAN_BLKS * 4;
  u32*   csr  = (u32*)ws; ws += (size_t)E * 4;
  u16* Tni = (u16*)ws; ws += 512 * DIM * 2;
  u16* Tei = (u16*)ws; ws += 384 * DIM * 2;
  u16* Tno = (u16*)ws; ws += DIM * DIM * 2;
  u16* Teo = (u16*)ws; ws += DIM * DIM * 2;

  float* xout = (float*)d_out;
  float* eout = xout + (size_t)N * DIM;

  k_prep<<<256, 256, 0, stream>>>(Wni, Wei, Wno, Weo, Tni, Tei, Tno, Teo, deg, N);
  k_count<<<512, 256, 0, stream>>>(tail, deg, E);
  k_scan_part<<<SCAN_BLKS, 256, 0, stream>>>(deg, part, N);
  k_scan_mid<<<1, 256, 0, stream>>>(part);
  k_scan_fin<<<SCAN_BLKS, 256, 0, stream>>>(deg, part, off, cur, N);
  k_fill<<<512, 256, 0, stream>>>(tail, cur, csr, E);
  k_node_in<<<NB128, 512, 0, stream>>>(x, Tni, nm, N);
  k_edge_in<<<EB, 512, 0, stream>>>(ea, Tei, Teo, nm, head, tail, ebias, beo, em, eout, E);
  k_node_agg<<<(N + 3) / 4, 256, 0, stream>>>(em, nm, off, deg, csr, nbias, hbuf, N);
  k_node_out<<<NB64, 256, 0, stream>>>(x, hbuf, Tno, bno, xout, N);
}

// Round 10
// 571.227 us; speedup vs baseline: 1.3868x; 1.3868x over previous
//
#include <hip/hip_runtime.h>
#include <hip/hip_bf16.h>
#include <math.h>

typedef short bf16x8 __attribute__((ext_vector_type(8)));
typedef float f32x4 __attribute__((ext_vector_type(4)));
typedef unsigned int u32;
typedef unsigned short u16;

#define DIM 128
#define ATTN_EPS 3.1622776601683794e-4f   // float(sqrt(1e-7))
#define DIV_EPS 1e-7f
#define SCAN_BLKS 256

__device__ __forceinline__ u16 f2b(float f) {            // f32 -> bf16 bits (RNE)
  u32 u = __float_as_uint(f);
  return (u16)((u + 0x7FFFu + ((u >> 16) & 1u)) >> 16);
}
__device__ __forceinline__ float b2f(u16 s) { return __uint_as_float(((u32)s) << 16); }
// mish(v) = v*tanh(softplus(v)) = v*(w^2-1)/(w^2+1), w = 1+e^v  (clamped: v>15 -> tanh==1)
__device__ __forceinline__ float mish_f(float v) {
  float e = __expf(fminf(v, 15.f));
  float w = 1.f + e;
  return v * (1.f - 2.f * __builtin_amdgcn_rcpf(w * w + 1.f));
}

// ---- staging helpers: tiles are [rows][136] u16 (pad +8 breaks 256B bank stride) ----
template <int NT, int NR>
__device__ __forceinline__ void stage_f32(u16 (*dst)[136], const float* __restrict__ src,
                                          long rowbase, long nrows, int tid) {
  #pragma unroll
  for (int it = 0; it < NR * 16 / NT; ++it) {
    int i = it * NT + tid;
    int r = i >> 4, c = (i & 15) * 8;
    long gr = rowbase + r;
    bf16x8 v;
    if (gr < nrows) {
      const f32x4* p = (const f32x4*)(src + gr * (long)DIM + c);
      f32x4 a = p[0], b = p[1];
      #pragma unroll
      for (int j = 0; j < 4; ++j) { v[j] = (short)f2b(a[j]); v[j + 4] = (short)f2b(b[j]); }
    } else {
      #pragma unroll
      for (int j = 0; j < 8; ++j) v[j] = 0;
    }
    *(bf16x8*)&dst[r][c] = v;
  }
}

template <int NT, int NR>
__device__ __forceinline__ void stage_b16(u16 (*dst)[136], const u16* __restrict__ src, int tid) {
  #pragma unroll
  for (int it = 0; it < NR * 16 / NT; ++it) {
    int i = it * NT + tid;
    int r = i >> 4, c = (i & 15) * 8;
    *(bf16x8*)&dst[r][c] = *(const bf16x8*)&src[(long)r * DIM + c];
  }
}

// gather nm[idx[row]][segoff..segoff+128) into LDS tile, vectorized 16B/lane
template <int NT, int NR>
__device__ __forceinline__ void gather_nm(u16 (*dst)[136], const u16* __restrict__ nm,
    const int* __restrict__ idx, int segoff, long rowbase, long nrows, int tid) {
  #pragma unroll
  for (int it = 0; it < NR * 16 / NT; ++it) {
    int i = it * NT + tid;
    int r = i >> 4, c = (i & 15) * 8;
    long gr = rowbase + r;
    bf16x8 v;
    if (gr < nrows) {
      v = *(const bf16x8*)&nm[(long)idx[gr] * 512 + segoff + c];
    } else {
      #pragma unroll
      for (int j = 0; j < 8; ++j) v[j] = 0;
    }
    *(bf16x8*)&dst[r][c] = v;
  }
}

// ---- MFMA cores, A and B from LDS. C/D: col=lane&15, row=(lane>>4)*4+j (verified) ----
__device__ __forceinline__ void mm_32x64(const u16 (*As)[136], const u16 (*Bs)[136],
                                         int wr, int wc, int lane, f32x4 acc[2][4]) {
  int r0 = wr * 32 + (lane & 15);
  int cb = wc * 64 + (lane & 15);
  int koff = (lane >> 4) * 8;
  #pragma unroll
  for (int ks = 0; ks < 4; ++ks) {
    int k = ks * 32 + koff;
    bf16x8 a0 = *(const bf16x8*)&As[r0][k];
    bf16x8 a1 = *(const bf16x8*)&As[r0 + 16][k];
    #pragma unroll
    for (int ct = 0; ct < 4; ++ct) {
      bf16x8 b = *(const bf16x8*)&Bs[cb + ct * 16][k];
      acc[0][ct] = __builtin_amdgcn_mfma_f32_16x16x32_bf16(a0, b, acc[0][ct], 0, 0, 0);
      acc[1][ct] = __builtin_amdgcn_mfma_f32_16x16x32_bf16(a1, b, acc[1][ct], 0, 0, 0);
    }
  }
}

// 32x32 output tile per wave (used by the fused agg+out kernel)
__device__ __forceinline__ void mm_32x32(const u16 (*As)[136], const u16 (*Bs)[136],
                                         int wr, int wc, int lane, f32x4 acc[2][2]) {
  int r0 = wr * 32 + (lane & 15);
  int cb = wc * 32 + (lane & 15);
  int koff = (lane >> 4) * 8;
  #pragma unroll
  for (int ks = 0; ks < 4; ++ks) {
    int k = ks * 32 + koff;
    bf16x8 a0 = *(const bf16x8*)&As[r0][k];
    bf16x8 a1 = *(const bf16x8*)&As[r0 + 16][k];
    #pragma unroll
    for (int ct = 0; ct < 2; ++ct) {
      bf16x8 b = *(const bf16x8*)&Bs[cb + ct * 16][k];
      acc[0][ct] = __builtin_amdgcn_mfma_f32_16x16x32_bf16(a0, b, acc[0][ct], 0, 0, 0);
      acc[1][ct] = __builtin_amdgcn_mfma_f32_16x16x32_bf16(a1, b, acc[1][ct], 0, 0, 0);
    }
  }
}

// ---- prep: transpose weights to [Cout][K] bf16 + zero deg ----
__global__ void k_prep(const float* __restrict__ Wni, const float* __restrict__ Wei,
                       const float* __restrict__ Wno, const float* __restrict__ Weo,
                       u16* __restrict__ Tni, u16* __restrict__ Tei,
                       u16* __restrict__ Tno, u16* __restrict__ Teo,
                       u32* __restrict__ deg, int N) {
  int stride = gridDim.x * blockDim.x;
  int t0 = blockIdx.x * blockDim.x + threadIdx.x;
  for (int i = t0; i < 128 * 512; i += stride) { int k = i >> 9, c = i & 511; Tni[c * 128 + k] = f2b(Wni[i]); }
  for (int i = t0; i < 128 * 384; i += stride) { int k = i / 384, c = i % 384; Tei[c * 128 + k] = f2b(Wei[i]); }
  for (int i = t0; i < 128 * 128; i += stride) { int k = i >> 7, c = i & 127; Tno[c * 128 + k] = f2b(Wno[i]); }
  for (int i = t0; i < 128 * 128; i += stride) { int k = i >> 7, c = i & 127; Teo[c * 128 + k] = f2b(Weo[i]); }
  for (int i = t0; i < N; i += stride) deg[i] = 0;
}

// ---- node input GEMM: nm[N][512] = bf16(x) @ W_node_in; x staged ONCE, 4 chunk loop ----
__global__ __launch_bounds__(512, 4) void k_node_in(const float* __restrict__ x,
    const u16* __restrict__ Tni, u16* __restrict__ nm, int N) {
  __shared__ u16 As[128][136];
  __shared__ u16 Bs[128][136];
  int tid = threadIdx.x, lane = tid & 63;
  int wid = tid >> 6, wr = wid >> 1, wc = wid & 1;
  long rowbase = (long)blockIdx.x * 128;
  stage_f32<512, 128>(As, x, rowbase, N, tid);
  stage_b16<512, 128>(Bs, Tni, tid);
  __syncthreads();
  #pragma unroll 1
  for (int chunk = 0; chunk < 4; ++chunk) {
    f32x4 acc[2][4] = {};
    mm_32x64(As, Bs, wr, wc, lane, acc);
    __syncthreads();                                       // Bs reads done
    if (chunk < 3) stage_b16<512, 128>(Bs, Tni + (chunk + 1) * 128 * DIM, tid);
    #pragma unroll
    for (int rt = 0; rt < 2; ++rt)
    #pragma unroll
    for (int j = 0; j < 4; ++j) {
      int lr = wr * 32 + rt * 16 + ((lane >> 4) << 2) + j;
      long r = rowbase + lr;
      if (r >= N) continue;
      #pragma unroll
      for (int ct = 0; ct < 4; ++ct) {
        int col = wc * 64 + ct * 16 + (lane & 15);
        nm[r * 512 + chunk * 128 + col] = f2b(acc[rt][ct][j]);
      }
    }
    if (chunk < 3) __syncthreads();                        // new Bs staged
  }
}

// ---- edge pass (R7 known-good, 368us): 3 input GEMMs, em (val|msg) edge-order,
//      fused mish + edge-output GEMM. All tiles LDS-staged, plain barriers. ----
__global__ __launch_bounds__(512, 4) void k_edge_in(const float* __restrict__ ea,
    const u16* __restrict__ Tei, const u16* __restrict__ Teo,
    const u16* __restrict__ nm, const int* __restrict__ head, const int* __restrict__ tail,
    const float* __restrict__ ebias, const float* __restrict__ beo,
    u32* __restrict__ em, float* __restrict__ eout, int E) {
  __shared__ u16 As[128][136];   // ea tile -> t2e -> H (mish) tile
  __shared__ u16 Bs[128][136];   // W_e2t -> W_msg -> n2n -> W_e2s -> h2e -> W_eo
  int tid = threadIdx.x, lane = tid & 63;
  int wid = tid >> 6, wr = wid >> 1, wc = wid & 1;   // 8 waves: 4 row x 2 col
  long rowbase = (long)blockIdx.x * 128;
  int col0 = wc * 64 + (lane & 15);

  stage_f32<512, 128>(As, ea, rowbase, E, tid);
  stage_b16<512, 128>(Bs, Tei + 128 * DIM, tid);       // edge_to_tail cols
  __syncthreads();
  f32x4 acc_t[2][4] = {};
  mm_32x64(As, Bs, wr, wc, lane, acc_t);
  __syncthreads();
  stage_b16<512, 128>(Bs, Tei + 256 * DIM, tid);       // attn-message cols
  __syncthreads();
  f32x4 acc_m[2][4] = {};
  mm_32x64(As, Bs, wr, wc, lane, acc_m);
  __syncthreads();
  gather_nm<512, 128>(Bs, nm, head, 128, rowbase, E, tid);   // n2n[head]
  __syncthreads();
  // epilogue 1: em[r][col] = pack(bf16(n2n + e2t), bf16(msg))
  #pragma unroll
  for (int rt = 0; rt < 2; ++rt)
  #pragma unroll
  for (int j = 0; j < 4; ++j) {
    int lr = wr * 32 + rt * 16 + ((lane >> 4) << 2) + j;
    long r = rowbase + lr;
    if (r < E) {
      #pragma unroll
      for (int ct = 0; ct < 4; ++ct) {
        int col = col0 + ct * 16;
        float n2n = b2f(Bs[lr][col]);
        em[r * 128 + col] = (u32)f2b(n2n + acc_t[rt][ct][j])
                          | ((u32)f2b(acc_m[rt][ct][j]) << 16);
      }
    }
  }
  __syncthreads();
  stage_b16<512, 128>(Bs, Tei, tid);                   // edge_to_self cols
  __syncthreads();
  f32x4 acc_s[2][4] = {};
  mm_32x64(As, Bs, wr, wc, lane, acc_s);               // last use of ea tile
  __syncthreads();
  gather_nm<512, 128>(Bs, nm, head, 256, rowbase, E, tid);   // h2e
  gather_nm<512, 128>(As, nm, tail, 384, rowbase, E, tid);   // t2e (As dead)
  __syncthreads();
  // epilogue 2: H = bf16(mish(e2s + h2e + t2e + eb)), in place over t2e (owner slots)
  #pragma unroll
  for (int rt = 0; rt < 2; ++rt)
  #pragma unroll
  for (int j = 0; j < 4; ++j) {
    int lr = wr * 32 + rt * 16 + ((lane >> 4) << 2) + j;
    long r = rowbase + lr;
    #pragma unroll
    for (int ct = 0; ct < 4; ++ct) {
      int col = col0 + ct * 16;
      if (r < E) {
        float epre = acc_s[rt][ct][j] + b2f(Bs[lr][col]) + b2f(As[lr][col]) + ebias[col];
        As[lr][col] = f2b(mish_f(epre));
      } else {
        As[lr][col] = 0;
      }
    }
  }
  __syncthreads();
  stage_b16<512, 128>(Bs, Teo, tid);                   // W_edge_out^T
  __syncthreads();
  f32x4 acc_o[2][4] = {};
  mm_32x64(As, Bs, wr, wc, lane, acc_o);
  #pragma unroll
  for (int rt = 0; rt < 2; ++rt)
  #pragma unroll
  for (int j = 0; j < 4; ++j) {
    int lr = wr * 32 + rt * 16 + ((lane >> 4) << 2) + j;
    long r = rowbase + lr;
    if (r >= E) continue;
    #pragma unroll
    for (int ct = 0; ct < 4; ++ct) {
      int col = col0 + ct * 16;
      eout[r * DIM + col] = ea[r * DIM + col] + acc_o[rt][ct][j] + beo[col];
    }
  }
}

// ---- CSR build ----
__global__ void k_count(const int* __restrict__ tail, u32* __restrict__ deg, int E) {
  int i = blockIdx.x * blockDim.x + threadIdx.x;
  int stride = gridDim.x * blockDim.x;
  for (; i < E; i += stride) atomicAdd(&deg[tail[i]], 1u);
}
__global__ __launch_bounds__(256) void k_scan_part(const u32* __restrict__ deg,
                                                   u32* __restrict__ part, int N) {
  __shared__ u32 red[256];
  int tid = threadIdx.x, b = blockIdx.x;
  int chunk = (N + SCAN_BLKS - 1) / SCAN_BLKS;
  int lo = b * chunk, hi = min(lo + chunk, N);
  u32 s = 0;
  for (int i = lo + tid; i < hi; i += 256) s += deg[i];
  red[tid] = s; __syncthreads();
  for (int st = 128; st > 0; st >>= 1) { if (tid < st) red[tid] += red[tid + st]; __syncthreads(); }
  if (tid == 0) part[b] = red[0];
}
__global__ __launch_bounds__(256) void k_scan_mid(u32* __restrict__ part) {
  __shared__ u32 lds[256];
  int tid = threadIdx.x;
  u32 v = part[tid];
  lds[tid] = v; __syncthreads();
  for (int s = 1; s < 256; s <<= 1) {
    u32 a = (tid >= s) ? lds[tid - s] : 0; __syncthreads();
    lds[tid] += a; __syncthreads();
  }
  part[tid] = lds[tid] - v;   // exclusive
}
__global__ __launch_bounds__(256) void k_scan_fin(const u32* __restrict__ deg,
    const u32* __restrict__ part, u32* __restrict__ off, u32* __restrict__ cur, int N) {
  __shared__ u32 lds[256];
  int tid = threadIdx.x, b = blockIdx.x;
  int chunk = (N + SCAN_BLKS - 1) / SCAN_BLKS;
  int lo = b * chunk, hi = min(lo + chunk, N);
  u32 carry = part[b];
  for (int base = lo; base < hi; base += 256) {
    int i = base + tid;
    u32 v = (i < hi) ? deg[i] : 0;
    lds[tid] = v; __syncthreads();
    for (int s = 1; s < 256; s <<= 1) {
      u32 a = (tid >= s) ? lds[tid - s] : 0; __syncthreads();
      lds[tid] += a; __syncthreads();
    }
    u32 incl = lds[tid], total = lds[255];
    __syncthreads();
    if (i < hi) { u32 o = carry + incl - v; off[i] = o; cur[i] = o; }
    carry += total;
  }
}
__global__ void k_fill(const int* __restrict__ tail, u32* __restrict__ cur,
                       u32* __restrict__ csr, int E) {
  int i = blockIdx.x * blockDim.x + threadIdx.x;
  int stride = gridDim.x * blockDim.x;
  for (; i < E; i += stride) { u32 p = atomicAdd(&cur[tail[i]], 1u); csr[p] = (u32)i; }
}

// ---- fused: 8 waves x 8 nodes agg (online softmax, 4-deep loads) -> LDS H tile
//      -> 64x128 out-GEMM + residual.  LDS 52.2KB -> 3 blocks/CU. ----
__global__ __launch_bounds__(512, 6) void k_agg_out(const u32* __restrict__ em,
    const u16* __restrict__ nm, const u32* __restrict__ off, const u32* __restrict__ deg,
    const u32* __restrict__ csr, const float* __restrict__ nbias, const float* __restrict__ x,
    const u16* __restrict__ Tno, const float* __restrict__ bno,
    float* __restrict__ xout, int N) {
  __shared__ u16 Hs[64][136];
  __shared__ u16 Bs[128][136];
  int tid = threadIdx.x, lane = tid & 63, wid = tid >> 6;
  long rowbase = (long)blockIdx.x * 64;
  int ch = lane * 2;
  stage_b16<512, 128>(Bs, Tno, tid);                   // W_node_out while aggregating
  float nb0 = nbias[ch], nb1 = nbias[ch + 1];
  #pragma unroll 1
  for (int s = 0; s < 8; ++s) {
    int lr = wid * 8 + s;
    long node = rowbase + lr;
    u32 hpack = 0;
    if (node < N) {
      u32 o = __builtin_amdgcn_readfirstlane(off[node]);
      u32 d = __builtin_amdgcn_readfirstlane(deg[node]);
      float m0 = -INFINITY, m1 = -INFINITY;
      float s0 = 0.f, s1 = 0.f, v0 = 0.f, v1 = 0.f, sv0 = 0.f, sv1 = 0.f;
      for (u32 i = 0; i < d; i += 4) {
        uint2 b[4];
        #pragma unroll
        for (int j = 0; j < 4; ++j) {
          if (i + j < d) {
            u32 e = csr[o + i + j];
            b[j] = *(const uint2*)(em + (long)e * 128 + ch);
          } else {
            b[j].x = 0xFF800000u; b[j].y = 0xFF800000u;   // val=0, msg=-inf (neutral)
          }
        }
        #pragma unroll
        for (int j = 0; j < 4; ++j) {
          float val0 = b2f((u16)(b[j].x & 0xffff)), g0 = b2f((u16)(b[j].x >> 16));
          float val1 = b2f((u16)(b[j].y & 0xffff)), g1 = b2f((u16)(b[j].y >> 16));
          float nmx0 = fmaxf(m0, g0);
          float sc0 = __expf(m0 - nmx0), pe0 = __expf(g0 - nmx0);
          s0 = s0 * sc0 + pe0; v0 = v0 * sc0 + pe0 * val0; sv0 += val0; m0 = nmx0;
          float nmx1 = fmaxf(m1, g1);
          float sc1 = __expf(m1 - nmx1), pe1 = __expf(g1 - nmx1);
          s1 = s1 * sc1 + pe1; v1 = v1 * sc1 + pe1 * val1; sv1 += val1; m1 = nmx1;
        }
      }
      // weight_e = exp(msg-M)+eps  =>  Σw = s + d*eps ; Σ(w*val) = v + eps*Σval
      float de = (float)d * ATTN_EPS;
      float r0 = (v0 + ATTN_EPS * sv0) * __builtin_amdgcn_rcpf(s0 + de + DIV_EPS);
      float r1 = (v1 + ATTN_EPS * sv1) * __builtin_amdgcn_rcpf(s1 + de + DIV_EPS);
      u32 np = *(const u32*)&nm[node * 512 + ch];
      float h0 = mish_f(r0 + b2f((u16)(np & 0xffff)) + nb0);
      float h1 = mish_f(r1 + b2f((u16)(np >> 16)) + nb1);
      hpack = (u32)f2b(h0) | ((u32)f2b(h1) << 16);
    }
    *(u32*)&Hs[lr][ch] = hpack;
  }
  __syncthreads();
  // out-GEMM: 8 waves = 2 row-groups x 4 col-groups of 32x32
  int wr = wid >> 2, wc = wid & 3;
  f32x4 acc[2][2] = {};
  mm_32x32(Hs, Bs, wr, wc, lane, acc);
  #pragma unroll
  for (int rt = 0; rt < 2; ++rt)
  #pragma unroll
  for (int j = 0; j < 4; ++j) {
    int lr = wr * 32 + rt * 16 + ((lane >> 4) << 2) + j;
    long r = rowbase + lr;
    if (r >= N) continue;
    #pragma unroll
    for (int ct = 0; ct < 2; ++ct) {
      int col = wc * 32 + ct * 16 + (lane & 15);
      xout[r * DIM + col] = x[r * DIM + col] + acc[rt][ct][j] + bno[col];
    }
  }
}

extern "C" void kernel_launch(void* const* d_in, const int* in_sizes, int n_in,
                              void* d_out, int out_size, void* d_ws, size_t ws_size,
                              hipStream_t stream) {
  const float* x     = (const float*)d_in[0];
  const float* ea    = (const float*)d_in[1];
  const int*   head  = (const int*)d_in[2];
  const int*   tail  = (const int*)d_in[3];
  const float* Wni   = (const float*)d_in[8];
  const float* Wei   = (const float*)d_in[9];
  const float* nbias = (const float*)d_in[10];
  const float* ebias = (const float*)d_in[11];
  const float* Wno   = (const float*)d_in[12];
  const float* bno   = (const float*)d_in[13];
  const float* Weo   = (const float*)d_in[14];
  const float* beo   = (const float*)d_in[15];
  const int N = in_sizes[0] / DIM;
  const int E = in_sizes[1] / DIM;
  const int NB64 = (N + 63) / 64;
  const int NB128 = (N + 127) / 128;
  const int EB = (E + 127) / 128;

  char* ws = (char*)d_ws;
  u16*   nm   = (u16*)ws; ws += (size_t)N * 512 * 2;      // node messages bf16 [N][512]
  u32*   em   = (u32*)ws; ws += (size_t)E * 128 * 4;      // packed val|msg, edge order [E][128]
  u32*   deg  = (u32*)ws; ws += (size_t)N * 4;
  u32*   off  = (u32*)ws; ws += (size_t)N * 4;
  u32*   cur  = (u32*)ws; ws += (size_t)N * 4;
  u32*   part = (u32*)ws; ws += (size_t)SCAN_BLKS * 4;
  u32*   csr  = (u32*)ws; ws += (size_t)E * 4;
  u16* Tni = (u16*)ws; ws += 512 * DIM * 2;
  u16* Tei = (u16*)ws; ws += 384 * DIM * 2;
  u16* Tno = (u16*)ws; ws += DIM * DIM * 2;
  u16* Teo = (u16*)ws; ws += DIM * DIM * 2;

  float* xout = (float*)d_out;
  float* eout = xout + (size_t)N * DIM;

  k_prep<<<256, 256, 0, stream>>>(Wni, Wei, Wno, Weo, Tni, Tei, Tno, Teo, deg, N);
  k_count<<<512, 256, 0, stream>>>(tail, deg, E);
  k_scan_part<<<SCAN_BLKS, 256, 0, stream>>>(deg, part, N);
  k_scan_mid<<<1, 256, 0, stream>>>(part);
  k_scan_fin<<<SCAN_BLKS, 256, 0, stream>>>(deg, part, off, cur, N);
  k_fill<<<512, 256, 0, stream>>>(tail, cur, csr, E);
  k_node_in<<<NB128, 512, 0, stream>>>(x, Tni, nm, N);
  k_edge_in<<<EB, 512, 0, stream>>>(ea, Tei, Teo, nm, head, tail, ebias, beo, em, eout, E);
  k_agg_out<<<NB64, 512, 0, stream>>>(em, nm, off, deg, csr, nbias, x, Tno, bno, xout, N);
}

// Round 11
// 556.549 us; speedup vs baseline: 1.4234x; 1.0264x over previous
//
#include <hip/hip_runtime.h>
#include <hip/hip_bf16.h>
#include <math.h>

typedef short bf16x8 __attribute__((ext_vector_type(8)));
typedef float f32x4 __attribute__((ext_vector_type(4)));
typedef unsigned int u32;
typedef unsigned short u16;

#define DIM 128
#define ATTN_EPS 3.1622776601683794e-4f   // float(sqrt(1e-7))
#define DIV_EPS 1e-7f
#define SCAN_BLKS 256

__device__ __forceinline__ u16 f2b(float f) {            // f32 -> bf16 bits (RNE)
  u32 u = __float_as_uint(f);
  return (u16)((u + 0x7FFFu + ((u >> 16) & 1u)) >> 16);
}
__device__ __forceinline__ float b2f(u16 s) { return __uint_as_float(((u32)s) << 16); }
// mish(v) = v*tanh(softplus(v)) = v*(w^2-1)/(w^2+1), w = 1+e^v  (clamped: v>15 -> tanh==1)
__device__ __forceinline__ float mish_f(float v) {
  float e = __expf(fminf(v, 15.f));
  float w = 1.f + e;
  return v * (1.f - 2.f * __builtin_amdgcn_rcpf(w * w + 1.f));
}

// ---- staging helpers: tiles are [rows][136] u16 (pad +8 breaks 256B bank stride) ----
template <int NT, int NR>
__device__ __forceinline__ void stage_f32(u16 (*dst)[136], const float* __restrict__ src,
                                          long rowbase, long nrows, int tid) {
  #pragma unroll
  for (int it = 0; it < NR * 16 / NT; ++it) {
    int i = it * NT + tid;
    int r = i >> 4, c = (i & 15) * 8;
    long gr = rowbase + r;
    bf16x8 v;
    if (gr < nrows) {
      const f32x4* p = (const f32x4*)(src + gr * (long)DIM + c);
      f32x4 a = p[0], b = p[1];
      #pragma unroll
      for (int j = 0; j < 4; ++j) { v[j] = (short)f2b(a[j]); v[j + 4] = (short)f2b(b[j]); }
    } else {
      #pragma unroll
      for (int j = 0; j < 8; ++j) v[j] = 0;
    }
    *(bf16x8*)&dst[r][c] = v;
  }
}

template <int NT, int NR>
__device__ __forceinline__ void stage_b16(u16 (*dst)[136], const u16* __restrict__ src, int tid) {
  #pragma unroll
  for (int it = 0; it < NR * 16 / NT; ++it) {
    int i = it * NT + tid;
    int r = i >> 4, c = (i & 15) * 8;
    *(bf16x8*)&dst[r][c] = *(const bf16x8*)&src[(long)r * DIM + c];
  }
}

// gather nm[idx[row]][segoff..segoff+128) into LDS tile, vectorized 16B/lane
template <int NT, int NR>
__device__ __forceinline__ void gather_nm(u16 (*dst)[136], const u16* __restrict__ nm,
    const int* __restrict__ idx, int segoff, long rowbase, long nrows, int tid) {
  #pragma unroll
  for (int it = 0; it < NR * 16 / NT; ++it) {
    int i = it * NT + tid;
    int r = i >> 4, c = (i & 15) * 8;
    long gr = rowbase + r;
    bf16x8 v;
    if (gr < nrows) {
      v = *(const bf16x8*)&nm[(long)idx[gr] * 512 + segoff + c];
    } else {
      #pragma unroll
      for (int j = 0; j < 8; ++j) v[j] = 0;
    }
    *(bf16x8*)&dst[r][c] = v;
  }
}

// ---- MFMA core, A and B from LDS. C/D: col=lane&15, row=(lane>>4)*4+j (verified) ----
__device__ __forceinline__ void mm_32x64(const u16 (*As)[136], const u16 (*Bs)[136],
                                         int wr, int wc, int lane, f32x4 acc[2][4]) {
  int r0 = wr * 32 + (lane & 15);
  int cb = wc * 64 + (lane & 15);
  int koff = (lane >> 4) * 8;
  #pragma unroll
  for (int ks = 0; ks < 4; ++ks) {
    int k = ks * 32 + koff;
    bf16x8 a0 = *(const bf16x8*)&As[r0][k];
    bf16x8 a1 = *(const bf16x8*)&As[r0 + 16][k];
    #pragma unroll
    for (int ct = 0; ct < 4; ++ct) {
      bf16x8 b = *(const bf16x8*)&Bs[cb + ct * 16][k];
      acc[0][ct] = __builtin_amdgcn_mfma_f32_16x16x32_bf16(a0, b, acc[0][ct], 0, 0, 0);
      acc[1][ct] = __builtin_amdgcn_mfma_f32_16x16x32_bf16(a1, b, acc[1][ct], 0, 0, 0);
    }
  }
}

// ---- prep: transpose weights to [Cout][K] bf16 + zero deg ----
__global__ void k_prep(const float* __restrict__ Wni, const float* __restrict__ Wei,
                       const float* __restrict__ Wno, const float* __restrict__ Weo,
                       u16* __restrict__ Tni, u16* __restrict__ Tei,
                       u16* __restrict__ Tno, u16* __restrict__ Teo,
                       u32* __restrict__ deg, int N) {
  int stride = gridDim.x * blockDim.x;
  int t0 = blockIdx.x * blockDim.x + threadIdx.x;
  for (int i = t0; i < 128 * 512; i += stride) { int k = i >> 9, c = i & 511; Tni[c * 128 + k] = f2b(Wni[i]); }
  for (int i = t0; i < 128 * 384; i += stride) { int k = i / 384, c = i % 384; Tei[c * 128 + k] = f2b(Wei[i]); }
  for (int i = t0; i < 128 * 128; i += stride) { int k = i >> 7, c = i & 127; Tno[c * 128 + k] = f2b(Wno[i]); }
  for (int i = t0; i < 128 * 128; i += stride) { int k = i >> 7, c = i & 127; Teo[c * 128 + k] = f2b(Weo[i]); }
  for (int i = t0; i < N; i += stride) deg[i] = 0;
}

// ---- node input GEMM: nm[N][512] = bf16(x) @ W_node_in; x staged ONCE, 4 chunk loop ----
__global__ __launch_bounds__(512, 4) void k_node_in(const float* __restrict__ x,
    const u16* __restrict__ Tni, u16* __restrict__ nm, int N) {
  __shared__ u16 As[128][136];
  __shared__ u16 Bs[128][136];
  int tid = threadIdx.x, lane = tid & 63;
  int wid = tid >> 6, wr = wid >> 1, wc = wid & 1;
  long rowbase = (long)blockIdx.x * 128;
  stage_f32<512, 128>(As, x, rowbase, N, tid);
  stage_b16<512, 128>(Bs, Tni, tid);
  __syncthreads();
  #pragma unroll 1
  for (int chunk = 0; chunk < 4; ++chunk) {
    f32x4 acc[2][4] = {};
    mm_32x64(As, Bs, wr, wc, lane, acc);
    __syncthreads();                                       // Bs reads done
    if (chunk < 3) stage_b16<512, 128>(Bs, Tni + (chunk + 1) * 128 * DIM, tid);
    #pragma unroll
    for (int rt = 0; rt < 2; ++rt)
    #pragma unroll
    for (int j = 0; j < 4; ++j) {
      int lr = wr * 32 + rt * 16 + ((lane >> 4) << 2) + j;
      long r = rowbase + lr;
      if (r >= N) continue;
      #pragma unroll
      for (int ct = 0; ct < 4; ++ct) {
        int col = wc * 64 + ct * 16 + (lane & 15);
        nm[r * 512 + chunk * 128 + col] = f2b(acc[rt][ct][j]);
      }
    }
    if (chunk < 3) __syncthreads();                        // new Bs staged
  }
}

// ---- edge pass (known-good 368us): 3 input GEMMs, em (val|msg) edge-order,
//      fused mish + edge-output GEMM. All tiles LDS-staged, plain barriers. ----
__global__ __launch_bounds__(512, 4) void k_edge_in(const float* __restrict__ ea,
    const u16* __restrict__ Tei, const u16* __restrict__ Teo,
    const u16* __restrict__ nm, const int* __restrict__ head, const int* __restrict__ tail,
    const float* __restrict__ ebias, const float* __restrict__ beo,
    u32* __restrict__ em, float* __restrict__ eout, int E) {
  __shared__ u16 As[128][136];   // ea tile -> t2e -> H (mish) tile
  __shared__ u16 Bs[128][136];   // W_e2t -> W_msg -> n2n -> W_e2s -> h2e -> W_eo
  int tid = threadIdx.x, lane = tid & 63;
  int wid = tid >> 6, wr = wid >> 1, wc = wid & 1;   // 8 waves: 4 row x 2 col
  long rowbase = (long)blockIdx.x * 128;
  int col0 = wc * 64 + (lane & 15);

  stage_f32<512, 128>(As, ea, rowbase, E, tid);
  stage_b16<512, 128>(Bs, Tei + 128 * DIM, tid);       // edge_to_tail cols
  __syncthreads();
  f32x4 acc_t[2][4] = {};
  mm_32x64(As, Bs, wr, wc, lane, acc_t);
  __syncthreads();
  stage_b16<512, 128>(Bs, Tei + 256 * DIM, tid);       // attn-message cols
  __syncthreads();
  f32x4 acc_m[2][4] = {};
  mm_32x64(As, Bs, wr, wc, lane, acc_m);
  __syncthreads();
  gather_nm<512, 128>(Bs, nm, head, 128, rowbase, E, tid);   // n2n[head]
  __syncthreads();
  // epilogue 1: em[r][col] = pack(bf16(n2n + e2t), bf16(msg))
  #pragma unroll
  for (int rt = 0; rt < 2; ++rt)
  #pragma unroll
  for (int j = 0; j < 4; ++j) {
    int lr = wr * 32 + rt * 16 + ((lane >> 4) << 2) + j;
    long r = rowbase + lr;
    if (r < E) {
      #pragma unroll
      for (int ct = 0; ct < 4; ++ct) {
        int col = col0 + ct * 16;
        float n2n = b2f(Bs[lr][col]);
        em[r * 128 + col] = (u32)f2b(n2n + acc_t[rt][ct][j])
                          | ((u32)f2b(acc_m[rt][ct][j]) << 16);
      }
    }
  }
  __syncthreads();
  stage_b16<512, 128>(Bs, Tei, tid);                   // edge_to_self cols
  __syncthreads();
  f32x4 acc_s[2][4] = {};
  mm_32x64(As, Bs, wr, wc, lane, acc_s);               // last use of ea tile
  __syncthreads();
  gather_nm<512, 128>(Bs, nm, head, 256, rowbase, E, tid);   // h2e
  gather_nm<512, 128>(As, nm, tail, 384, rowbase, E, tid);   // t2e (As dead)
  __syncthreads();
  // epilogue 2: H = bf16(mish(e2s + h2e + t2e + eb)), in place over t2e (owner slots)
  #pragma unroll
  for (int rt = 0; rt < 2; ++rt)
  #pragma unroll
  for (int j = 0; j < 4; ++j) {
    int lr = wr * 32 + rt * 16 + ((lane >> 4) << 2) + j;
    long r = rowbase + lr;
    #pragma unroll
    for (int ct = 0; ct < 4; ++ct) {
      int col = col0 + ct * 16;
      if (r < E) {
        float epre = acc_s[rt][ct][j] + b2f(Bs[lr][col]) + b2f(As[lr][col]) + ebias[col];
        As[lr][col] = f2b(mish_f(epre));
      } else {
        As[lr][col] = 0;
      }
    }
  }
  __syncthreads();
  stage_b16<512, 128>(Bs, Teo, tid);                   // W_edge_out^T
  __syncthreads();
  f32x4 acc_o[2][4] = {};
  mm_32x64(As, Bs, wr, wc, lane, acc_o);
  #pragma unroll
  for (int rt = 0; rt < 2; ++rt)
  #pragma unroll
  for (int j = 0; j < 4; ++j) {
    int lr = wr * 32 + rt * 16 + ((lane >> 4) << 2) + j;
    long r = rowbase + lr;
    if (r >= E) continue;
    #pragma unroll
    for (int ct = 0; ct < 4; ++ct) {
      int col = col0 + ct * 16;
      eout[r * DIM + col] = ea[r * DIM + col] + acc_o[rt][ct][j] + beo[col];
    }
  }
}

// ---- CSR build ----
__global__ void k_count(const int* __restrict__ tail, u32* __restrict__ deg, int E) {
  int i = blockIdx.x * blockDim.x + threadIdx.x;
  int stride = gridDim.x * blockDim.x;
  for (; i < E; i += stride) atomicAdd(&deg[tail[i]], 1u);
}
__global__ __launch_bounds__(256) void k_scan_part(const u32* __restrict__ deg,
                                                   u32* __restrict__ part, int N) {
  __shared__ u32 red[256];
  int tid = threadIdx.x, b = blockIdx.x;
  int chunk = (N + SCAN_BLKS - 1) / SCAN_BLKS;
  int lo = b * chunk, hi = min(lo + chunk, N);
  u32 s = 0;
  for (int i = lo + tid; i < hi; i += 256) s += deg[i];
  red[tid] = s; __syncthreads();
  for (int st = 128; st > 0; st >>= 1) { if (tid < st) red[tid] += red[tid + st]; __syncthreads(); }
  if (tid == 0) part[b] = red[0];
}
__global__ __launch_bounds__(256) void k_scan_mid(u32* __restrict__ part) {
  __shared__ u32 lds[256];
  int tid = threadIdx.x;
  u32 v = part[tid];
  lds[tid] = v; __syncthreads();
  for (int s = 1; s < 256; s <<= 1) {
    u32 a = (tid >= s) ? lds[tid - s] : 0; __syncthreads();
    lds[tid] += a; __syncthreads();
  }
  part[tid] = lds[tid] - v;   // exclusive
}
__global__ __launch_bounds__(256) void k_scan_fin(const u32* __restrict__ deg,
    const u32* __restrict__ part, u32* __restrict__ off, u32* __restrict__ cur, int N) {
  __shared__ u32 lds[256];
  int tid = threadIdx.x, b = blockIdx.x;
  int chunk = (N + SCAN_BLKS - 1) / SCAN_BLKS;
  int lo = b * chunk, hi = min(lo + chunk, N);
  u32 carry = part[b];
  for (int base = lo; base < hi; base += 256) {
    int i = base + tid;
    u32 v = (i < hi) ? deg[i] : 0;
    lds[tid] = v; __syncthreads();
    for (int s = 1; s < 256; s <<= 1) {
      u32 a = (tid >= s) ? lds[tid - s] : 0; __syncthreads();
      lds[tid] += a; __syncthreads();
    }
    u32 incl = lds[tid], total = lds[255];
    __syncthreads();
    if (i < hi) { u32 o = carry + incl - v; off[i] = o; cur[i] = o; }
    carry += total;
  }
}
__global__ void k_fill(const int* __restrict__ tail, u32* __restrict__ cur,
                       u32* __restrict__ csr, int E) {
  int i = blockIdx.x * blockDim.x + threadIdx.x;
  int stride = gridDim.x * blockDim.x;
  for (; i < E; i += stride) { u32 p = atomicAdd(&cur[tail[i]], 1u); csr[p] = (u32)i; }
}

// ---- per-node gather + online softmax + divide + mish -> hbuf; 1 node/wave,
//      4-deep batched loads (pads are val=0,msg=-inf: algebraically neutral) ----
__global__ __launch_bounds__(256, 8) void k_node_agg(const u32* __restrict__ em,
    const u16* __restrict__ nm, const u32* __restrict__ off, const u32* __restrict__ deg,
    const u32* __restrict__ csr, const float* __restrict__ nbias,
    u16* __restrict__ hbuf, int N) {
  int tid = threadIdx.x, lane = tid & 63;
  int node = blockIdx.x * 4 + (tid >> 6);
  if (node >= N) return;
  int ch = lane * 2;
  u32 o = __builtin_amdgcn_readfirstlane(off[node]);
  u32 d = __builtin_amdgcn_readfirstlane(deg[node]);
  float m0 = -INFINITY, m1 = -INFINITY;
  float s0 = 0.f, s1 = 0.f, v0 = 0.f, v1 = 0.f, sv0 = 0.f, sv1 = 0.f;
  for (u32 i = 0; i < d; i += 4) {
    uint2 b[4];
    #pragma unroll
    for (int j = 0; j < 4; ++j) {
      if (i + j < d) {
        u32 e = csr[o + i + j];
        b[j] = *(const uint2*)(em + (long)e * 128 + ch);
      } else {
        b[j].x = 0xFF800000u; b[j].y = 0xFF800000u;   // val=0, msg=-inf
      }
    }
    #pragma unroll
    for (int j = 0; j < 4; ++j) {
      float val0 = b2f((u16)(b[j].x & 0xffff)), g0 = b2f((u16)(b[j].x >> 16));
      float val1 = b2f((u16)(b[j].y & 0xffff)), g1 = b2f((u16)(b[j].y >> 16));
      float nmx0 = fmaxf(m0, g0);
      float sc0 = __expf(m0 - nmx0), pe0 = __expf(g0 - nmx0);
      s0 = s0 * sc0 + pe0; v0 = v0 * sc0 + pe0 * val0; sv0 += val0; m0 = nmx0;
      float nmx1 = fmaxf(m1, g1);
      float sc1 = __expf(m1 - nmx1), pe1 = __expf(g1 - nmx1);
      s1 = s1 * sc1 + pe1; v1 = v1 * sc1 + pe1 * val1; sv1 += val1; m1 = nmx1;
    }
  }
  // weight_e = exp(msg-M)+eps  =>  Σw = s + d*eps ; Σ(w*val) = v + eps*Σval
  float de = (float)d * ATTN_EPS;
  float r0 = (v0 + ATTN_EPS * sv0) * __builtin_amdgcn_rcpf(s0 + de + DIV_EPS);
  float r1 = (v1 + ATTN_EPS * sv1) * __builtin_amdgcn_rcpf(s1 + de + DIV_EPS);
  u32 np = *(const u32*)&nm[(long)node * 512 + ch];
  float h0 = mish_f(r0 + b2f((u16)(np & 0xffff)) + nbias[ch]);
  float h1 = mish_f(r1 + b2f((u16)(np >> 16)) + nbias[ch + 1]);
  *(u32*)&hbuf[(long)node * 128 + ch] = (u32)f2b(h0) | ((u32)f2b(h1) << 16);
}

// ---- node output: x_out = x + h @ W_node_out + b ----
__global__ __launch_bounds__(256) void k_node_out(const float* __restrict__ x,
    const u16* __restrict__ hbuf, const u16* __restrict__ Tno, const float* __restrict__ bno,
    float* __restrict__ xout, int N) {
  __shared__ u16 As[64][136];
  __shared__ u16 Bs[128][136];
  int tid = threadIdx.x, lane = tid & 63;
  int wid = tid >> 6, wr = wid >> 1, wc = wid & 1;
  long rowbase = (long)blockIdx.x * 64;
  stage_b16<256, 64>(As, hbuf + rowbase * DIM, tid);   // hbuf padded to tile multiple
  stage_b16<256, 128>(Bs, Tno, tid);
  __syncthreads();
  f32x4 acc[2][4] = {};
  mm_32x64(As, Bs, wr, wc, lane, acc);
  #pragma unroll
  for (int rt = 0; rt < 2; ++rt)
  #pragma unroll
  for (int j = 0; j < 4; ++j) {
    int lr = wr * 32 + rt * 16 + ((lane >> 4) << 2) + j;
    long r = rowbase + lr;
    if (r >= N) continue;
    #pragma unroll
    for (int ct = 0; ct < 4; ++ct) {
      int col = wc * 64 + ct * 16 + (lane & 15);
      xout[r * DIM + col] = x[r * DIM + col] + acc[rt][ct][j] + bno[col];
    }
  }
}

extern "C" void kernel_launch(void* const* d_in, const int* in_sizes, int n_in,
                              void* d_out, int out_size, void* d_ws, size_t ws_size,
                              hipStream_t stream) {
  const float* x     = (const float*)d_in[0];
  const float* ea    = (const float*)d_in[1];
  const int*   head  = (const int*)d_in[2];
  const int*   tail  = (const int*)d_in[3];
  const float* Wni   = (const float*)d_in[8];
  const float* Wei   = (const float*)d_in[9];
  const float* nbias = (const float*)d_in[10];
  const float* ebias = (const float*)d_in[11];
  const float* Wno   = (const float*)d_in[12];
  const float* bno   = (const float*)d_in[13];
  const float* Weo   = (const float*)d_in[14];
  const float* beo   = (const float*)d_in[15];
  const int N = in_sizes[0] / DIM;
  const int E = in_sizes[1] / DIM;
  const int NB64 = (N + 63) / 64;
  const int NB128 = (N + 127) / 128;
  const int EB = (E + 127) / 128;
  const int NPAD = NB64 * 64;

  char* ws = (char*)d_ws;
  u16*   nm   = (u16*)ws; ws += (size_t)N * 512 * 2;      // node messages bf16 [N][512]
  u32*   em   = (u32*)ws; ws += (size_t)E * 128 * 4;      // packed val|msg, edge order [E][128]
  u16*   hbuf = (u16*)ws; ws += (size_t)NPAD * 128 * 2;   // mish(node path) bf16
  u32*   deg  = (u32*)ws; ws += (size_t)N * 4;
  u32*   off  = (u32*)ws; ws += (size_t)N * 4;
  u32*   cur  = (u32*)ws; ws += (size_t)N * 4;
  u32*   part = (u32*)ws; ws += (size_t)SCAN_BLKS * 4;
  u32*   csr  = (u32*)ws; ws += (size_t)E * 4;
  u16* Tni = (u16*)ws; ws += 512 * DIM * 2;
  u16* Tei = (u16*)ws; ws += 384 * DIM * 2;
  u16* Tno = (u16*)ws; ws += DIM * DIM * 2;
  u16* Teo = (u16*)ws; ws += DIM * DIM * 2;

  float* xout = (float*)d_out;
  float* eout = xout + (size_t)N * DIM;

  k_prep<<<256, 256, 0, stream>>>(Wni, Wei, Wno, Weo, Tni, Tei, Tno, Teo, deg, N);
  k_count<<<512, 256, 0, stream>>>(tail, deg, E);
  k_scan_part<<<SCAN_BLKS, 256, 0, stream>>>(deg, part, N);
  k_scan_mid<<<1, 256, 0, stream>>>(part);
  k_scan_fin<<<SCAN_BLKS, 256, 0, stream>>>(deg, part, off, cur, N);
  k_fill<<<512, 256, 0, stream>>>(tail, cur, csr, E);
  k_node_in<<<NB128, 512, 0, stream>>>(x, Tni, nm, N);
  k_edge_in<<<EB, 512, 0, stream>>>(ea, Tei, Teo, nm, head, tail, ebias, beo, em, eout, E);
  k_node_agg<<<(N + 3) / 4, 256, 0, stream>>>(em, nm, off, deg, csr, nbias, hbuf, N);
  k_node_out<<<NB64, 256, 0, stream>>>(x, hbuf, Tno, bno, xout, N);
}